// Round 9
// baseline (462.615 us; speedup 1.0000x reference)
//
#include <hip/hip_runtime.h>

typedef __attribute__((ext_vector_type(4))) float f32x4;
typedef __attribute__((ext_vector_type(8))) short short8;

#define C_    512
#define HW_   1024
#define M_    2048
#define TN    32
#define NTILE 8
#define NKC   16
#define NCAND 16
#define NEG_INF (-1e30f)

// ---- LDS arena (bytes) ----
#define ATT_STRIDE 264                 // bf16 per row (256 + 8 pad)
#define BUF0 32768                     // att16 buffer 0 [32][264] bf16 = 16896
#define BUF1 49664                     // att16 buffer 1
#define ARENA_SIZE 66560               // -> 2 blocks/CU
// overlays:
//  [0,32768)  A bf16 [32][1024B] XOR-swz (GEMM) -> qs f32 [32][260] (refine; spills
//             512B into BUF0 base - candv dead there by then)
//  BUF0 region post-scan: candv@32768 [32][33]f, candi@36992, selidx@41216,
//                         refv@43264, w_lds@45312, i_lds@46336
#define CV_BASE  32768
#define CI_BASE  36992
#define SEL_BASE 41216
#define RFV_BASE 43264
#define WL_BASE  45312
#define IL_BASE  46336
#define QS 260

__device__ __forceinline__ unsigned short f2bf(float f) {
    unsigned u = __builtin_bit_cast(unsigned, f);
    u += 0x7fffu + ((u >> 16) & 1u);     // RNE
    return (unsigned short)(u >> 16);
}
__device__ __forceinline__ float bf2f(unsigned short s) {
    return __builtin_bit_cast(float, (unsigned)s << 16);
}

// ---- repack mempool [2048][512] f32 -> membR bf16, kc-major (32ch chunks) ----
__global__ __launch_bounds__(256) void convk(const float* __restrict__ in,
                                             unsigned short* __restrict__ ob) {
    int gid = blockIdx.x * 256 + threadIdx.x;
    int m  = gid >> 6;
    int ug = gid & 63;
    const float4* p = (const float4*)(in + (size_t)m * C_ + ug * 8);
    float4 v0 = p[0], v1 = p[1];
    int4 o;
    o.x = (int)f2bf(v0.x) | ((int)f2bf(v0.y) << 16);
    o.y = (int)f2bf(v0.z) | ((int)f2bf(v0.w) << 16);
    o.z = (int)f2bf(v1.x) | ((int)f2bf(v1.y) << 16);
    o.w = (int)f2bf(v1.z) | ((int)f2bf(v1.w) << 16);
    int kc = ug >> 2, u = ug & 3;
    *(int4*)((char*)ob + (size_t)kc * 131072 + m * 64 + (u << 4)) = o;
}

__device__ __forceinline__ void scan_tile(const unsigned short* arow, int m0,
                                          float* sv, int* si, int stq) {
#pragma unroll
    for (int v = 0; v < 8; ++v) {
        short8 pv = *(const short8*)(arow + stq * 8 + v * 32);
        float f[8];
#pragma unroll
        for (int e = 0; e < 8; ++e) f[e] = bf2f((unsigned short)pv[e]);
        float m01 = fmaxf(f[0], f[1]), m23 = fmaxf(f[2], f[3]);
        float m45 = fmaxf(f[4], f[5]), m67 = fmaxf(f[6], f[7]);
        float vmax = fmaxf(fmaxf(m01, m23), fmaxf(m45, m67));
        if (vmax > sv[0]) {
#pragma unroll
            for (int e = 0; e < 8; ++e) {
                if (f[e] > sv[0]) {
                    sv[0] = f[e]; si[0] = m0 + stq * 8 + v * 32 + e;
#pragma unroll
                    for (int p = 0; p < 7; ++p) {
                        if (sv[p] > sv[p + 1]) {
                            float tv = sv[p]; sv[p] = sv[p + 1]; sv[p + 1] = tv;
                            int   ti = si[p]; si[p] = si[p + 1]; si[p + 1] = ti;
                        }
                    }
                }
            }
        }
    }
}

__global__ __launch_bounds__(256, 2) void memk(const float* __restrict__ x,
                                               const float* __restrict__ mempool,
                                               const unsigned short* __restrict__ membR,
                                               float* __restrict__ out) {
    __shared__ __align__(16) char arena[ARENA_SIZE];
    unsigned short* att0 = (unsigned short*)(arena + BUF0);
    unsigned short* att1 = (unsigned short*)(arena + BUF1);
    float* candv  = (float*)(arena + CV_BASE);              // [32][33]
    int*   candi  = (int*)(arena + CI_BASE);                // [32][33]
    int*   selidx = (int*)(arena + SEL_BASE);               // [32][16]
    float* refv   = (float*)(arena + RFV_BASE);             // [32][16]
    float* qs     = (float*)arena;                          // refine [32][260]
    float* w_lds  = (float*)(arena + WL_BASE);              // [32][8]
    int*   i_lds  = (int*)(arena + IL_BASE);                // [32][8]

    const int t   = threadIdx.x;
    const int l   = t & 63;
    const int w   = t >> 6;
    const int hi  = l >> 4;
    const int l15 = l & 15;
    const int n0  = blockIdx.x * TN;
    const int b   = n0 >> 10;
    const int hw0 = n0 & 1023;
    const float* xb = x + (size_t)b * C_ * HW_ + hw0;

    // ---- stage A once: x -> bf16, rows of 1024B, 16B-unit XOR swizzle by row ----
    {
        const int row = t & 31, g = t >> 5;
        const float* xp = xb + row;
        char* Arow = arena + row * 1024;
        const int swz = (row & 7) << 4;
#pragma unroll 8
        for (int j = 0; j < 32; ++j) {
            int c = g * 64 + 2 * j;
            float f0 = xp[(size_t)c * HW_];
            float f1 = xp[(size_t)(c + 1) * HW_];
            unsigned pk = (unsigned)f2bf(f0) | ((unsigned)f2bf(f1) << 16);
            *(unsigned*)(Arow + ((2 * c) ^ swz)) = pk;
        }
    }
    __syncthreads();

    // per-thread running top-8 (ascending), 4 threads/row (t<128 scan)
    const int srow = t >> 2, stq = t & 3;
    float sv[8]; int si[8];
#pragma unroll
    for (int p = 0; p < 8; ++p) { sv[p] = NEG_INF; si[p] = 0x7fffffff; }

    const int aswz = (l15 & 7) << 4;
    const char* Ab0 = arena + l15 * 1024;
    const char* Ab1 = arena + (16 + l15) * 1024;
    const int hio = hi << 4;
    const char* bbase = (const char*)membR + w * 4096 + l15 * 64 + hi * 16;

    // depth-3 B prefetch pipeline over linear steps s = tile*16+kc
    short8 bq[4], b1[4], b2[4];
#pragma unroll
    for (int itf = 0; itf < 4; ++itf) {
        bq[itf] = *(const short8*)(bbase + itf * 1024);
        b1[itf] = *(const short8*)(bbase + 131072 + itf * 1024);
        b2[itf] = *(const short8*)(bbase + 262144 + itf * 1024);
    }

    for (int tile = 0; tile < NTILE; ++tile) {
        unsigned short* dumpBuf = (tile & 1) ? att1 : att0;
        unsigned short* scanBuf = (tile & 1) ? att0 : att1;

        f32x4 acc[2][4];
#pragma unroll
        for (int rf = 0; rf < 2; ++rf)
#pragma unroll
            for (int itf = 0; itf < 4; ++itf) acc[rf][itf] = (f32x4)0.f;

#pragma unroll 4
        for (int kc = 0; kc < NKC; ++kc) {
            int s3 = tile * NKC + kc + 3;
            if (s3 > 127) s3 = 127;
            const char* pn = bbase + (size_t)(s3 & 15) * 131072 + (size_t)(s3 >> 4) * 16384;
            short8 bn[4];
#pragma unroll
            for (int itf = 0; itf < 4; ++itf) bn[itf] = *(const short8*)(pn + itf * 1024);

            const int ao = (kc * 64 + hio) ^ aswz;
            short8 a0 = *(const short8*)(Ab0 + ao);
            short8 a1 = *(const short8*)(Ab1 + ao);
#pragma unroll
            for (int itf = 0; itf < 4; ++itf) {
                acc[0][itf] = __builtin_amdgcn_mfma_f32_16x16x32_bf16(a0, bq[itf], acc[0][itf], 0, 0, 0);
                acc[1][itf] = __builtin_amdgcn_mfma_f32_16x16x32_bf16(a1, bq[itf], acc[1][itf], 0, 0, 0);
            }
#pragma unroll
            for (int itf = 0; itf < 4; ++itf) { bq[itf] = b1[itf]; b1[itf] = b2[itf]; b2[itf] = bn[itf]; }
        }

        // ---- dump att bf16 into dumpBuf ----
#pragma unroll
        for (int rf = 0; rf < 2; ++rf)
#pragma unroll
            for (int itf = 0; itf < 4; ++itf) {
                int col = w * 64 + itf * 16 + l15;
#pragma unroll
                for (int reg = 0; reg < 4; ++reg)
                    dumpBuf[(rf * 16 + hi * 4 + reg) * ATT_STRIDE + col] = f2bf(acc[rf][itf][reg]);
            }

        // ---- scan previous tile (off critical path; other buffer) ----
        if (tile > 0 && t < 128)
            scan_tile(scanBuf + srow * ATT_STRIDE, (tile - 1) * 256, sv, si, stq);

        __syncthreads();   // dump(t) visible; scan(t-1) complete
    }
    // final tile's scan (buf of tile 7 = att1)
    if (t < 128)
        scan_tile(att1 + srow * ATT_STRIDE, 7 * 256, sv, si, stq);

    // ---- candidates: [row][33] (candv overlays buf0: tile6 data, already scanned) ----
    if (t < 128) {
#pragma unroll
        for (int p = 0; p < 8; ++p) {
            candv[srow * 33 + stq * 8 + p] = sv[p];
            candi[srow * 33 + stq * 8 + p] = si[p];
        }
    }
    __syncthreads();

    // ---- leader: 4-way merge of sorted lists -> approx top-16 ----
    if (t < TN) {
        const int row = t;
        int pos[4] = {7, 7, 7, 7};
        for (int s = 0; s < NCAND; ++s) {
            float vb = NEG_INF; int ib = 0x7fffffff; int qb = 0;
#pragma unroll
            for (int q = 0; q < 4; ++q) {
                if (pos[q] >= 0) {
                    float v = candv[row * 33 + q * 8 + pos[q]];
                    int  ii = candi[row * 33 + q * 8 + pos[q]];
                    if (v > vb || (v == vb && ii < ib)) { vb = v; ib = ii; qb = q; }
                }
            }
            selidx[row * NCAND + s] = ib;
#pragma unroll
            for (int q = 0; q < 4; ++q) if (q == qb) --pos[q];
        }
    }
    __syncthreads();

    // ---- exact fp32 refine, T14 split-staging ----
    int cnd[2];
    cnd[0] = selidx[t];
    cnd[1] = selidx[t + 256];
    float racc[2] = {0.f, 0.f};
    const int qr = t & 31, qg = t >> 5;
    const float* xq = xb + qr;

    // chunk0: load + write
    f32x4 r0[8];
#pragma unroll 2
    for (int j = 0; j < 8; ++j) {
        int c = qg * 32 + j * 4;
        r0[j][0] = xq[(size_t)(c + 0) * HW_];
        r0[j][1] = xq[(size_t)(c + 1) * HW_];
        r0[j][2] = xq[(size_t)(c + 2) * HW_];
        r0[j][3] = xq[(size_t)(c + 3) * HW_];
    }
#pragma unroll
    for (int j = 0; j < 8; ++j) *(f32x4*)&qs[qr * QS + qg * 32 + j * 4] = r0[j];
    __syncthreads();

    // issue chunk1 loads early (hide under chunk0 compute)
    f32x4 r1[8];
#pragma unroll 2
    for (int j = 0; j < 8; ++j) {
        int c = 256 + qg * 32 + j * 4;
        r1[j][0] = xq[(size_t)(c + 0) * HW_];
        r1[j][1] = xq[(size_t)(c + 1) * HW_];
        r1[j][2] = xq[(size_t)(c + 2) * HW_];
        r1[j][3] = xq[(size_t)(c + 3) * HW_];
    }
    // compute chunk0
#pragma unroll
    for (int pp = 0; pp < 2; ++pp) {
        const int row = (t + 256 * pp) >> 4;
        const float4* mp = (const float4*)(mempool + (size_t)cnd[pp] * C_);
        const f32x4* qrow = (const f32x4*)&qs[row * QS];
        float a = racc[pp];
#pragma unroll 8
        for (int u = 0; u < 64; ++u) {
            f32x4 q4 = qrow[u];
            float4 m4 = mp[u];
            a = fmaf(q4[0], m4.x, a);
            a = fmaf(q4[1], m4.y, a);
            a = fmaf(q4[2], m4.z, a);
            a = fmaf(q4[3], m4.w, a);
        }
        racc[pp] = a;
    }
    __syncthreads();
#pragma unroll
    for (int j = 0; j < 8; ++j) *(f32x4*)&qs[qr * QS + qg * 32 + j * 4] = r1[j];
    __syncthreads();
#pragma unroll
    for (int pp = 0; pp < 2; ++pp) {
        const int row = (t + 256 * pp) >> 4;
        const float4* mp = (const float4*)(mempool + (size_t)cnd[pp] * C_ + 256);
        const f32x4* qrow = (const f32x4*)&qs[row * QS];
        float a = racc[pp];
#pragma unroll 8
        for (int u = 0; u < 64; ++u) {
            f32x4 q4 = qrow[u];
            float4 m4 = mp[u];
            a = fmaf(q4[0], m4.x, a);
            a = fmaf(q4[1], m4.y, a);
            a = fmaf(q4[2], m4.z, a);
            a = fmaf(q4[3], m4.w, a);
        }
        racc[pp] = a;
    }
    refv[t] = racc[0];
    refv[t + 256] = racc[1];
    __syncthreads();

    // ---- leader: exact top-8 of 16 + softmax ----
    if (t < TN) {
        const int row = t;
        float rv[16]; int ri[16];
#pragma unroll
        for (int s = 0; s < 16; ++s) { rv[s] = refv[row * 16 + s]; ri[s] = selidx[row * 16 + s]; }
        float wv8[8]; int wi8[8];
#pragma unroll
        for (int sel = 0; sel < 8; ++sel) {
            float vb = NEG_INF; int ib = 0x7fffffff; int sb = 0;
            for (int s = 0; s < 16; ++s) {
                if (rv[s] > vb || (rv[s] == vb && ri[s] < ib)) { vb = rv[s]; ib = ri[s]; sb = s; }
            }
            rv[sb] = NEG_INF;
            wv8[sel] = vb; wi8[sel] = ib;
        }
        const float mx = wv8[0];
        float e[8]; float sum = 0.f;
#pragma unroll
        for (int j = 0; j < 8; ++j) { e[j] = expf(wv8[j] - mx); sum += e[j]; }
        const float inv = 1.f / sum;
#pragma unroll
        for (int j = 0; j < 8; ++j) { w_lds[row * 8 + j] = e[j] * inv; i_lds[row * 8 + j] = wi8[j]; }
    }
    __syncthreads();

    // ---- combine: gathered mempool float4, coalesced-pair stores ----
    const int crow = t & 31;
    const int cw   = t >> 5;      // 0..7, 64 channels each
    float wreg[8]; int ireg[8];
#pragma unroll
    for (int j = 0; j < 8; ++j) { wreg[j] = w_lds[crow * 8 + j]; ireg[j] = i_lds[crow * 8 + j]; }
    float* outb = out + (size_t)b * C_ * HW_ + hw0 + crow;
#pragma unroll 2
    for (int cg = 0; cg < 16; ++cg) {
        const int c = cw * 64 + cg * 4;
        float o0 = 0.f, o1 = 0.f, o2 = 0.f, o3 = 0.f;
#pragma unroll
        for (int j = 0; j < 8; ++j) {
            const float4 mp4 = *(const float4*)&mempool[(size_t)ireg[j] * C_ + c];
            o0 = fmaf(wreg[j], mp4.x, o0);
            o1 = fmaf(wreg[j], mp4.y, o1);
            o2 = fmaf(wreg[j], mp4.z, o2);
            o3 = fmaf(wreg[j], mp4.w, o3);
        }
        outb[(size_t)(c + 0) * HW_] = o0;
        outb[(size_t)(c + 1) * HW_] = o1;
        outb[(size_t)(c + 2) * HW_] = o2;
        outb[(size_t)(c + 3) * HW_] = o3;
    }
}

extern "C" void kernel_launch(void* const* d_in, const int* in_sizes, int n_in,
                              void* d_out, int out_size, void* d_ws, size_t ws_size,
                              hipStream_t stream) {
    const float* x       = (const float*)d_in[0];
    const float* mempool = (const float*)d_in[1];
    unsigned short* membR = (unsigned short*)d_ws;   // 2 MiB bf16 repack
    float* o = (float*)d_out;
    convk<<<dim3(512), dim3(256), 0, stream>>>(mempool, membR);
    memk<<<dim3(1024), dim3(256), 0, stream>>>(x, mempool, membR, o);
}